// Round 2
// baseline (676.501 us; speedup 1.0000x reference)
//
#include <hip/hip_runtime.h>

// ===========================================================================
// CrossAttention (B=32, TF=2048, TP=256, F=768, P=512, A=512).
// Round 2: Q-GEMM fused into attention. One 512-thread kernel per 64-row
// Q-tile does: Qtile = frame@Wq+bq (into 64KB swizzled LDS), E = Q K^T
// (+mask -> out1), softmax, O = P K, LN(concat(O,Q)) -> out0.
// Kp/KpT prepared by small kernels as before.  160KB LDS, 8 waves, 1 blk/CU.
// ===========================================================================

typedef __bf16 bf16x8 __attribute__((ext_vector_type(8)));
typedef __bf16 bf16x4 __attribute__((ext_vector_type(4)));
typedef float  f32x4  __attribute__((ext_vector_type(4)));
typedef int    i32x4  __attribute__((ext_vector_type(4)));
typedef int    i32x2  __attribute__((ext_vector_type(2)));
typedef unsigned short u16;

__device__ __forceinline__ u16 f2b(float f) {   // round-to-nearest-even
  union { float f; unsigned int i; } v; v.f = f;
  unsigned int u = v.i;
  return (u16)((u + 0x7FFFu + ((u >> 16) & 1u)) >> 16);
}
__device__ __forceinline__ bf16x8 ldfrag(const void* p) {
  return __builtin_bit_cast(bf16x8, *(const i32x4*)p);
}
__device__ __forceinline__ f32x4 mfma16(bf16x8 a, bf16x8 b, f32x4 c) {
  return __builtin_amdgcn_mfma_f32_16x16x32_bf16(a, b, c, 0, 0, 0);
}
// async global->LDS, 16B per lane; LDS dest is wave-uniform base + lane*16
__device__ __forceinline__ void gl_lds16(const void* g, void* l) {
  __builtin_amdgcn_global_load_lds(
      (const __attribute__((address_space(1))) void*)g,
      (__attribute__((address_space(3))) void*)l, 16, 0, 0);
}

// --------------------------------------------------------------------------
// out[C][R] (bf16) = in[R][C]^T (fp32). For weights.
// --------------------------------------------------------------------------
__global__ void transpose_f32_bf16(const float* __restrict__ in, u16* __restrict__ out,
                                   int R, int C) {
  __shared__ u16 tile[32][33];
  int c0 = blockIdx.x * 32, r0 = blockIdx.y * 32;
  int x = threadIdx.x, y = threadIdx.y;  // x:0..31, y:0..7
#pragma unroll
  for (int i = 0; i < 32; i += 8) tile[y + i][x] = f2b(in[(size_t)(r0 + y + i) * C + c0 + x]);
  __syncthreads();
#pragma unroll
  for (int i = 0; i < 32; i += 8) out[(size_t)(c0 + y + i) * R + r0 + x] = tile[x][y + i];
}

// --------------------------------------------------------------------------
// bf16 2D transpose, batched via blockIdx.z (for Kp -> KpT).
// --------------------------------------------------------------------------
__global__ void transpose_bf16(const u16* __restrict__ in, u16* __restrict__ out,
                               int R, int C, long inStride, long outStride) {
  __shared__ u16 tile[32][33];
  long bb = blockIdx.z;
  in  += bb * inStride;
  out += bb * outStride;
  int c0 = blockIdx.x * 32, r0 = blockIdx.y * 32;
  int x = threadIdx.x, y = threadIdx.y;
#pragma unroll
  for (int i = 0; i < 32; i += 8) tile[y + i][x] = in[(size_t)(r0 + y + i) * C + c0 + x];
  __syncthreads();
#pragma unroll
  for (int i = 0; i < 32; i += 8) out[(size_t)(c0 + y + i) * R + r0 + x] = tile[x][y + i];
}

// --------------------------------------------------------------------------
// C[M][N] (bf16) = A[M][K](fp32 conv) @ Bt[N][K]^T (bf16) + bias[N].
// Round-1 structure (proven).  Used for the K projection only (grid 256).
// --------------------------------------------------------------------------
__global__ __launch_bounds__(256, 2) void gemm_bias_bt(
    const float* __restrict__ A, const u16* __restrict__ Bt,
    const float* __restrict__ bias, u16* __restrict__ C, int M, int N, int K) {
  __shared__ __align__(16) u16 As[2][128][72];
  __shared__ __align__(16) u16 Bs[2][128][64];
  int tid = threadIdx.x, wave = tid >> 6, lane = tid & 63;
  int l = lane & 15, q = lane >> 4;
  int wr = wave >> 1, wc = wave & 1;
  int chunk = gridDim.x >> 3;
  int swz = (blockIdx.x & 7) * chunk + (blockIdx.x >> 3);
  int n0 = (swz & 3) * 128, m0 = (swz >> 2) * 128;
  int aRow = tid >> 4, aCol = (tid & 15) * 4;
  int NT = K >> 6;
  int sw = ((lane & 7) ^ (lane >> 3)) << 4;

  f32x4 acc[4][4];
#pragma unroll
  for (int mt = 0; mt < 4; mt++)
#pragma unroll
    for (int nt = 0; nt < 4; nt++) acc[mt][nt] = (f32x4)0.0f;
  f32x4 pf[8];

  auto stageB = [&](int buf, int kc) {
#pragma unroll
    for (int i = 0; i < 4; i++) {
      int rb = wave * 4 + i;
      int r  = rb * 8 + (lane >> 3);
      const char* src = (const char*)Bt + ((size_t)(n0 + r) * K + kc) * 2 + sw;
      gl_lds16(src, (char*)&Bs[buf][0][0] + rb * 1024);
    }
  };
  auto loadA = [&](int kc) {
#pragma unroll
    for (int i = 0; i < 8; i++)
      pf[i] = *(const f32x4*)&A[(size_t)(m0 + aRow + i * 16) * K + kc + aCol];
  };
  auto writeA = [&](int buf) {
#pragma unroll
    for (int i = 0; i < 8; i++) {
      bf16x4 h;
#pragma unroll
      for (int j = 0; j < 4; j++) h[j] = (__bf16)pf[i][j];
      *(i32x2*)&As[buf][aRow + i * 16][aCol] = __builtin_bit_cast(i32x2, h);
    }
  };

  stageB(0, 0);
  loadA(0);
  writeA(0);
  __syncthreads();

  for (int t = 0; t < NT; t++) {
    int cur = t & 1, nxt = cur ^ 1;
    bool more = (t + 1 < NT);
    if (more) { stageB(nxt, (t + 1) << 6); loadA((t + 1) << 6); }
#pragma unroll
    for (int ks = 0; ks < 64; ks += 32) {
      bf16x8 af[4], bv[4];
#pragma unroll
      for (int mt = 0; mt < 4; mt++) af[mt] = ldfrag(&As[cur][wr * 64 + mt * 16 + l][ks + q * 8]);
#pragma unroll
      for (int nt = 0; nt < 4; nt++) {
        int row = wc * 64 + nt * 16 + l;
        bv[nt] = ldfrag((const char*)&Bs[cur][0][0] + row * 128 +
                        (((ks << 1) + q * 16) ^ ((l & 7) << 4)));
      }
#pragma unroll
      for (int mt = 0; mt < 4; mt++)
#pragma unroll
        for (int nt = 0; nt < 4; nt++) acc[mt][nt] = mfma16(af[mt], bv[nt], acc[mt][nt]);
    }
    if (more) writeA(nxt);
    __syncthreads();
  }

#pragma unroll
  for (int nt = 0; nt < 4; nt++) {
    int col = n0 + wc * 64 + nt * 16 + l;
    float bvv = bias[col];
#pragma unroll
    for (int mt = 0; mt < 4; mt++)
#pragma unroll
      for (int r = 0; r < 4; r++) {
        int row = m0 + wr * 64 + mt * 16 + q * 4 + r;
        C[(size_t)row * N + col] = f2b(acc[mt][nt][r] + bvv);
      }
  }
}

// --------------------------------------------------------------------------
// Fused Q-GEMM + attention.  512 threads (8 waves), grid 1024 (32 tiles x 32 b).
// LDS map (163840 B total):
//   [0,65536)       Qs: 64 rows x 1024B, XOR-swizzled (key row&7, 16B granule)
//   [65536,131072)  R1: phaseA Bs[2][512][64B] / phase1 Ks[2][256][128B]
//                   phase3 Ps[64][512B] at 65536 ; phase4 S1A/S2A at 65536+
//   [98304,163840)  phase3 Kts[2][512][64B]
//   [131072,141312) phaseA As[2][64][80B] ; phase2 SX/SS scratch at 131072+
// Wave w: rows rg=(w&1)*32 (mt 0..1); cols: phaseA (w>>1)*128, phase1 (w>>1)*64,
// phase3/4 (w>>1)*128.  Row-stat exchanges across waves with same (w&1).
// --------------------------------------------------------------------------
#define QS_OFF 0
#define R1_OFF 65536
#define PS_OFF 65536
#define KT_OFF 98304
#define AS_OFF 131072
#define SX_OFF 131072
#define SS_OFF 132096
#define S1A_OFF 65536
#define S2A_OFF 66560

__global__ __launch_bounds__(512, 2) void fused_qattn(
    const float* __restrict__ frame,  // [32][2048][768] fp32
    const u16* __restrict__ WqT,      // [512][768] bf16
    const float* __restrict__ bq,     // [512]
    const u16* __restrict__ Kp,       // [32*256][512] bf16
    const u16* __restrict__ KpT,      // [32][512][256] bf16
    const int* __restrict__ mask,     // [32][256]
    const float* __restrict__ gamma, const float* __restrict__ beta,  // [1024]
    float* __restrict__ out0,         // [32*2048][1024] fp32
    float* __restrict__ out1) {       // [32*2048][256] fp32
  __shared__ __align__(16) char smem[163840];

  int tid = threadIdx.x, wave = tid >> 6, lane = tid & 63;
  int l = lane & 15, q = lane >> 4;
  int rg = (wave & 1) * 32;

  // XCD-chunked swizzle (1024 % 8 == 0): 4 consecutive batches per XCD.
  int chunk = gridDim.x >> 3;
  int swz = (blockIdx.x & 7) * chunk + (blockIdx.x >> 3);
  int m0 = (swz & 31) * 64, b = swz >> 5;

  const float* Fb = frame + ((size_t)b * 2048 + m0) * 768;
  const u16* Kb  = Kp  + (size_t)b * 256 * 512;
  const u16* KTb = KpT + (size_t)b * 512 * 256;

  auto qs_ptr = [&](int row, int colb) -> u16* {
    return (u16*)(smem + QS_OFF + row * 1024 + (colb ^ ((row & 7) << 4)));
  };

  // ======== Phase A: Qs = frame_tile @ Wq + bq  (BK=32, dbuf, 24 steps) ====
  {
    int cgA = (wave >> 1) * 128;
    f32x4 accq[2][8];
#pragma unroll
    for (int mt = 0; mt < 2; mt++)
#pragma unroll
      for (int nt = 0; nt < 8; nt++) accq[mt][nt] = (f32x4)0.0f;
    f32x4 pf;

    int bsw = ((lane & 3) ^ ((lane >> 2) & 3)) << 4;
    auto stageB = [&](int buf, int kc) {
#pragma unroll
      for (int i = 0; i < 4; i++) {
        int c = wave * 4 + i;                 // chunk: 16 rows x 64B
        int row = c * 16 + (lane >> 2);
        const char* src = (const char*)WqT + ((size_t)row * 768 + kc) * 2 + bsw;
        gl_lds16(src, smem + R1_OFF + buf * 32768 + c * 1024);
      }
    };
    auto loadA = [&](int kc) {
      pf = *(const f32x4*)&Fb[(size_t)(tid >> 3) * 768 + kc + (tid & 7) * 4];
    };
    auto writeA = [&](int buf) {
      bf16x4 h;
#pragma unroll
      for (int j = 0; j < 4; j++) h[j] = (__bf16)pf[j];
      *(i32x2*)(smem + AS_OFF + buf * 5120 + (tid >> 3) * 80 + (tid & 7) * 8) =
          __builtin_bit_cast(i32x2, h);
    };

    stageB(0, 0); loadA(0); writeA(0);
    __syncthreads();
    for (int t = 0; t < 24; t++) {
      int cur = t & 1;
      bool more = (t < 23);
      if (more) { stageB(cur ^ 1, (t + 1) * 32); loadA((t + 1) * 32); }
      bf16x8 af[2], bv[8];
#pragma unroll
      for (int mt = 0; mt < 2; mt++)
        af[mt] = ldfrag(smem + AS_OFF + cur * 5120 + (rg + mt * 16 + l) * 80 + q * 16);
#pragma unroll
      for (int nt = 0; nt < 8; nt++) {
        int row = cgA + nt * 16 + l;
        bv[nt] = ldfrag(smem + R1_OFF + cur * 32768 + row * 64 +
                        ((q * 16) ^ ((l & 3) << 4)));
      }
      __builtin_amdgcn_s_setprio(1);
#pragma unroll
      for (int mt = 0; mt < 2; mt++)
#pragma unroll
        for (int nt = 0; nt < 8; nt++) accq[mt][nt] = mfma16(af[mt], bv[nt], accq[mt][nt]);
      __builtin_amdgcn_s_setprio(0);
      if (more) writeA(cur ^ 1);
      __syncthreads();
    }
    // epilogue: +bq, write swizzled bf16 Qs
#pragma unroll
    for (int nt = 0; nt < 8; nt++) {
      int col = cgA + nt * 16 + l;
      float bqv = bq[col];
#pragma unroll
      for (int mt = 0; mt < 2; mt++)
#pragma unroll
        for (int r = 0; r < 4; r++) {
          int row = rg + mt * 16 + q * 4 + r;
          *qs_ptr(row, col * 2) = f2b(accq[mt][nt][r] + bqv);
        }
    }
  }

  // ======== Phase 1: E = Q K^T  (kc 0..511 by 64, dbuf Ks) =================
  int cg1 = (wave >> 1) * 64;
  f32x4 accE[2][4];
#pragma unroll
  for (int mt = 0; mt < 2; mt++)
#pragma unroll
    for (int nt = 0; nt < 4; nt++) accE[mt][nt] = (f32x4)0.0f;

  int ksw = ((lane & 7) ^ (lane >> 3)) << 4;
  auto stageK = [&](int buf, int kc) {
#pragma unroll
    for (int i = 0; i < 4; i++) {
      int c = wave * 4 + i;                   // chunk: 8 rows x 128B
      int row = c * 8 + (lane >> 3);
      const char* src = (const char*)Kb + ((size_t)row * 512 + kc) * 2 + ksw;
      gl_lds16(src, smem + R1_OFF + buf * 32768 + c * 1024);
    }
  };

  stageK(0, 0);
  __syncthreads();   // Qs writes drained + Ks buf0 ready
#pragma unroll
  for (int t = 0; t < 8; t++) {
    int cur = t & 1;
    if (t < 7) stageK(cur ^ 1, (t + 1) * 64);
    __builtin_amdgcn_s_setprio(1);
#pragma unroll
    for (int s = 0; s < 2; s++) {
      bf16x8 af[2], bv[4];
#pragma unroll
      for (int mt = 0; mt < 2; mt++)
        af[mt] = ldfrag(qs_ptr(rg + mt * 16 + l, t * 128 + s * 64 + q * 16));
#pragma unroll
      for (int nt = 0; nt < 4; nt++) {
        int row = cg1 + nt * 16 + l;
        bv[nt] = ldfrag(smem + R1_OFF + cur * 32768 + row * 128 +
                        ((s * 64 + q * 16) ^ ((l & 7) << 4)));
      }
#pragma unroll
      for (int mt = 0; mt < 2; mt++)
#pragma unroll
        for (int nt = 0; nt < 4; nt++) accE[mt][nt] = mfma16(af[mt], bv[nt], accE[mt][nt]);
    }
    __builtin_amdgcn_s_setprio(0);
    __syncthreads();
  }

  // ======== Phase 2: mask, out1, softmax (cross-wave row stats), Ps ========
  float madd[4];
#pragma unroll
  for (int nt = 0; nt < 4; nt++)
    madd[nt] = (float)(1 - mask[b * 256 + cg1 + nt * 16 + l]) * -1000.0f;
#pragma unroll
  for (int mt = 0; mt < 2; mt++)
#pragma unroll
    for (int nt = 0; nt < 4; nt++)
#pragma unroll
      for (int r = 0; r < 4; r++) accE[mt][nt][r] += madd[nt];

  int rbase = m0 + rg + q * 4;
#pragma unroll
  for (int mt = 0; mt < 2; mt++)
#pragma unroll
    for (int r = 0; r < 4; r++) {
      size_t ro = ((size_t)b * 2048 + rbase + mt * 16 + r) * 256;
#pragma unroll
      for (int nt = 0; nt < 4; nt++) out1[ro + cg1 + nt * 16 + l] = accE[mt][nt][r];
    }

  float* SX = (float*)(smem + SX_OFF);
  float* SS = (float*)(smem + SS_OFF);
  float mx[2][4], sm[2][4], rs[2][4];
#pragma unroll
  for (int mt = 0; mt < 2; mt++)
#pragma unroll
    for (int r = 0; r < 4; r++) {
      float m = -1e30f;
#pragma unroll
      for (int nt = 0; nt < 4; nt++) m = fmaxf(m, accE[mt][nt][r]);
      mx[mt][r] = m;
    }
#pragma unroll
  for (int off = 1; off < 16; off <<= 1)
#pragma unroll
    for (int mt = 0; mt < 2; mt++)
#pragma unroll
      for (int r = 0; r < 4; r++) mx[mt][r] = fmaxf(mx[mt][r], __shfl_xor(mx[mt][r], off));
  if (l == 0)
#pragma unroll
    for (int mt = 0; mt < 2; mt++)
#pragma unroll
      for (int r = 0; r < 4; r++) SX[wave * 32 + mt * 16 + q * 4 + r] = mx[mt][r];
  __syncthreads();   // S1
#pragma unroll
  for (int mt = 0; mt < 2; mt++)
#pragma unroll
    for (int r = 0; r < 4; r++) {
      float m = mx[mt][r];
#pragma unroll
      for (int pw = 0; pw < 8; pw += 2) {
        int w2 = (wave & 1) + pw;
        if (w2 != wave) m = fmaxf(m, SX[w2 * 32 + mt * 16 + q * 4 + r]);
      }
      mx[mt][r] = m;
      sm[mt][r] = 0.0f;
    }
#pragma unroll
  for (int mt = 0; mt < 2; mt++)
#pragma unroll
    for (int nt = 0; nt < 4; nt++)
#pragma unroll
      for (int r = 0; r < 4; r++) {
        float p = __expf(accE[mt][nt][r] - mx[mt][r]);
        accE[mt][nt][r] = p;
        sm[mt][r] += p;
      }
#pragma unroll
  for (int off = 1; off < 16; off <<= 1)
#pragma unroll
    for (int mt = 0; mt < 2; mt++)
#pragma unroll
      for (int r = 0; r < 4; r++) sm[mt][r] += __shfl_xor(sm[mt][r], off);
  if (l == 0)
#pragma unroll
    for (int mt = 0; mt < 2; mt++)
#pragma unroll
      for (int r = 0; r < 4; r++) SS[wave * 32 + mt * 16 + q * 4 + r] = sm[mt][r];
  __syncthreads();   // S2
#pragma unroll
  for (int mt = 0; mt < 2; mt++)
#pragma unroll
    for (int r = 0; r < 4; r++) {
      float s = sm[mt][r];
#pragma unroll
      for (int pw = 0; pw < 8; pw += 2) {
        int w2 = (wave & 1) + pw;
        if (w2 != wave) s += SS[w2 * 32 + mt * 16 + q * 4 + r];
      }
      rs[mt][r] = 1.0f / s;
    }
  // Ps write (swizzled [64][512B]); phase-1 Ks reads ended at S1.
#pragma unroll
  for (int mt = 0; mt < 2; mt++)
#pragma unroll
    for (int r = 0; r < 4; r++) {
      int row = rg + mt * 16 + q * 4 + r;
#pragma unroll
      for (int nt = 0; nt < 4; nt++) {
        int col = cg1 + nt * 16 + l;
        *(u16*)(smem + PS_OFF + row * 512 + ((col * 2) ^ ((row & 7) << 4))) =
            f2b(accE[mt][nt][r] * rs[mt][r]);
      }
    }

  // ======== Phase 3: O = P @ Kp via KpT  (pc 0..255 by 32, dbuf Kts) =======
  int og3 = (wave >> 1) * 128;
  int tsw = ((lane & 3) ^ ((lane >> 2) & 3)) << 4;
  auto stageKt = [&](int buf, int pc) {
#pragma unroll
    for (int i = 0; i < 4; i++) {
      int c = wave * 4 + i;                   // chunk: 16 rows x 64B
      int row = c * 16 + (lane >> 2);
      const char* src = (const char*)KTb + ((size_t)row * 256 + pc) * 2 + tsw;
      gl_lds16(src, smem + KT_OFF + buf * 32768 + c * 1024);
    }
  };
  stageKt(0, 0);
  __syncthreads();   // S3: Ps visible + Kts buf0 ready

  f32x4 accO[2][8];
#pragma unroll
  for (int mt = 0; mt < 2; mt++)
#pragma unroll
    for (int nt = 0; nt < 8; nt++) accO[mt][nt] = (f32x4)0.0f;
#pragma unroll
  for (int t = 0; t < 8; t++) {
    int cur = t & 1, pc = t * 32;
    if (t < 7) stageKt(cur ^ 1, (t + 1) * 32);
    bf16x8 ps[2], bv[8];
#pragma unroll
    for (int mt = 0; mt < 2; mt++) {
      int row = rg + mt * 16 + l;
      ps[mt] = ldfrag(smem + PS_OFF + row * 512 + ((pc * 2 + q * 16) ^ ((l & 7) << 4)));
    }
    __builtin_amdgcn_s_setprio(1);
#pragma unroll
    for (int nt = 0; nt < 8; nt++) {
      int row = og3 + nt * 16 + l;
      bv[nt] = ldfrag(smem + KT_OFF + cur * 32768 + row * 64 +
                      ((q * 16) ^ ((l & 3) << 4)));
    }
#pragma unroll
    for (int mt = 0; mt < 2; mt++)
#pragma unroll
      for (int nt = 0; nt < 8; nt++) accO[mt][nt] = mfma16(ps[mt], bv[nt], accO[mt][nt]);
    __builtin_amdgcn_s_setprio(0);
    __syncthreads();
  }

  // ======== Phase 4: LN over concat(O[512], Q[512]) ========================
  float s1[2][4], s2[2][4];
#pragma unroll
  for (int mt = 0; mt < 2; mt++)
#pragma unroll
    for (int r = 0; r < 4; r++) { s1[mt][r] = 0.0f; s2[mt][r] = 0.0f; }
#pragma unroll
  for (int mt = 0; mt < 2; mt++)
#pragma unroll
    for (int nt = 0; nt < 8; nt++)
#pragma unroll
      for (int r = 0; r < 4; r++) {
        float v = accO[mt][nt][r];
        s1[mt][r] += v; s2[mt][r] += v * v;
      }
  // Q part: this wave sums Q cols og3 + l*8 .. +7 per row (cols partitioned
  // across the 4 col-waves sharing the row band).
#pragma unroll
  for (int mt = 0; mt < 2; mt++)
#pragma unroll
    for (int r = 0; r < 4; r++) {
      int row = rg + mt * 16 + q * 4 + r;
      bf16x8 qv = ldfrag(qs_ptr(row, (og3 + l * 8) * 2));
#pragma unroll
      for (int j = 0; j < 8; j++) {
        float v = (float)qv[j];
        s1[mt][r] += v; s2[mt][r] += v * v;
      }
    }
#pragma unroll
  for (int off = 1; off < 16; off <<= 1)
#pragma unroll
    for (int mt = 0; mt < 2; mt++)
#pragma unroll
      for (int r = 0; r < 4; r++) {
        s1[mt][r] += __shfl_xor(s1[mt][r], off);
        s2[mt][r] += __shfl_xor(s2[mt][r], off);
      }
  float* S1A = (float*)(smem + S1A_OFF);
  float* S2A = (float*)(smem + S2A_OFF);
  if (l == 0)
#pragma unroll
    for (int mt = 0; mt < 2; mt++)
#pragma unroll
      for (int r = 0; r < 4; r++) {
        S1A[wave * 32 + mt * 16 + q * 4 + r] = s1[mt][r];
        S2A[wave * 32 + mt * 16 + q * 4 + r] = s2[mt][r];
      }
  __syncthreads();   // S5
#pragma unroll
  for (int mt = 0; mt < 2; mt++)
#pragma unroll
    for (int r = 0; r < 4; r++) {
#pragma unroll
      for (int pw = 0; pw < 8; pw += 2) {
        int w2 = (wave & 1) + pw;
        if (w2 != wave) {
          s1[mt][r] += S1A[w2 * 32 + mt * 16 + q * 4 + r];
          s2[mt][r] += S2A[w2 * 32 + mt * 16 + q * 4 + r];
        }
      }
    }
#pragma unroll
  for (int mt = 0; mt < 2; mt++)
#pragma unroll
    for (int r = 0; r < 4; r++) {
      float mean = s1[mt][r] * (1.0f / 1024.0f);
      float var  = s2[mt][r] * (1.0f / 1024.0f) - mean * mean;
      float rstd = rsqrtf(var + 1e-5f);
      int row = rg + mt * 16 + q * 4 + r;
      size_t rowbase = ((size_t)b * 2048 + m0 + row) * 1024;
      // O half: cols og3..og3+127
#pragma unroll
      for (int nt = 0; nt < 8; nt++) {
        int col = og3 + nt * 16 + l;
        out0[rowbase + col] = (accO[mt][nt][r] - mean) * rstd * gamma[col] + beta[col];
      }
      // Q half: cols 512+og3+l*8 .. +7 (re-read Qs)
      bf16x8 qv = ldfrag(qs_ptr(row, (og3 + l * 8) * 2));
      float ov[8];
#pragma unroll
      for (int j = 0; j < 8; j++) {
        int col = 512 + og3 + l * 8 + j;
        ov[j] = ((float)qv[j] - mean) * rstd * gamma[col] + beta[col];
      }
      *(f32x4*)&out0[rowbase + 512 + og3 + l * 8]     = *(f32x4*)&ov[0];
      *(f32x4*)&out0[rowbase + 512 + og3 + l * 8 + 4] = *(f32x4*)&ov[4];
    }
}

// --------------------------------------------------------------------------
extern "C" void kernel_launch(void* const* d_in, const int* in_sizes, int n_in,
                              void* d_out, int out_size, void* d_ws, size_t ws_size,
                              hipStream_t stream) {
  (void)in_sizes; (void)n_in; (void)out_size; (void)ws_size;
  const float* frame = (const float*)d_in[0];   // [32][2048][768] fp32
  const float* phn   = (const float*)d_in[1];   // [32][256][512]  fp32
  const int*   msk   = (const int*)d_in[2];     // [32][256] int32
  const float* Wq    = (const float*)d_in[3];   // [768][512] fp32
  const float* bq    = (const float*)d_in[4];   // [512]
  const float* Wk    = (const float*)d_in[5];   // [512][512]
  const float* bk    = (const float*)d_in[6];   // [512]
  const float* gamma = (const float*)d_in[7];   // [1024]
  const float* beta  = (const float*)d_in[8];   // [1024]

  u16* ws   = (u16*)d_ws;
  u16* WqT  = ws;              // [512][768] bf16      393216 elems
  u16* WkT  = ws + 393216;     // [512][512]           262144
  u16* Kp   = ws + 655360;     // [8192][512]          4194304
  u16* KpT  = ws + 4849664;    // [32][512][256]       4194304  (end ~18 MB)

  float* out0 = (float*)d_out;                      // [32*2048][1024] fp32
  float* out1 = out0 + (size_t)32 * 2048 * 1024;    // [32*2048][256]  fp32

  transpose_f32_bf16<<<dim3(16, 24, 1), dim3(32, 8, 1), 0, stream>>>(Wq, WqT, 768, 512);
  transpose_f32_bf16<<<dim3(16, 16, 1), dim3(32, 8, 1), 0, stream>>>(Wk, WkT, 512, 512);
  gemm_bias_bt<<<dim3(256, 1, 1), dim3(256, 1, 1), 0, stream>>>(phn, WkT, bk, Kp, 8192, 512, 512);
  transpose_bf16<<<dim3(16, 8, 32), dim3(32, 8, 1), 0, stream>>>(Kp, KpT, 256, 512, 131072, 131072);
  fused_qattn<<<dim3(1024, 1, 1), dim3(512, 1, 1), 0, stream>>>(
      frame, WqT, bq, Kp, KpT, msk, gamma, beta, out0, out1);
}